// Round 14
// baseline (62.241 us; speedup 1.0000x reference)
//
#include <hip/hip_runtime.h>

#define NTOK 8192
#define DH   128
#define QBLK 128
#define KVB  64

typedef __attribute__((ext_vector_type(8)))  short bf16x8;
typedef __attribute__((ext_vector_type(16))) float f32x16;
typedef __attribute__((ext_vector_type(4)))  unsigned short u16x4;
typedef __attribute__((ext_vector_type(4)))  _Float16 h16x4;

typedef __attribute__((address_space(1))) const void gv_t;
typedef __attribute__((address_space(3))) void sv_t;

static __device__ __forceinline__ unsigned short f2bf(float x) {
  union { float f; unsigned int u; } a; a.f = x;
  unsigned int r = a.u + 0x7FFFu + ((a.u >> 16) & 1u);  // RNE
  return (unsigned short)(r >> 16);
}

static __device__ __forceinline__ unsigned pk2(float lo, float hi) {
  unsigned r;
  asm("v_cvt_pk_bf16_f32 %0, %1, %2" : "=v"(r) : "v"(lo), "v"(hi));
  return r;
}

static __device__ __forceinline__ float fexp2(float x) {
  float r;
  asm("v_exp_f32 %0, %1" : "=v"(r) : "v"(x));
  return r;
}

static __device__ __forceinline__ f32x16 zero16() {
  f32x16 v;
  #pragma unroll
  for (int i = 0; i < 16; ++i) v[i] = 0.f;
  return v;
}

// ---------------------------------------------------------------------------
// Pre-pass: bf16 "LDS images" of K (row-major, swizzle (row&15)<<4 @16B) and
// V^T (128 d-rows x 128B, swizzle (d&15)<<3 @8B), tiled by 64 kv (16KB/tile).
// ---------------------------------------------------------------------------
__global__ __launch_bounds__(256)
void fa_prep(const float* __restrict__ Kg, const float* __restrict__ Vg,
             char* __restrict__ Kimg, char* __restrict__ Vimg)
{
  const int t = blockIdx.x;
  const int tid = threadIdx.x;

  { // K tile: 64 rows x 256B
    const int krow = tid >> 2;
    const int kcg  = (tid & 3) * 32;
    const float* src = Kg + ((size_t)t * KVB + krow) * DH + kcg;
    char* drow = Kimg + (size_t)t * 16384 + krow * 256;
    const int sw = (krow & 15) << 4;
    #pragma unroll
    for (int w = 0; w < 4; ++w) {
      float4 a = *reinterpret_cast<const float4*>(src + w * 8);
      float4 b = *reinterpret_cast<const float4*>(src + w * 8 + 4);
      union { bf16x8 v; unsigned short u[8]; } f;
      f.u[0] = f2bf(a.x); f.u[1] = f2bf(a.y); f.u[2] = f2bf(a.z); f.u[3] = f2bf(a.w);
      f.u[4] = f2bf(b.x); f.u[5] = f2bf(b.y); f.u[6] = f2bf(b.z); f.u[7] = f2bf(b.w);
      *reinterpret_cast<bf16x8*>(drow + ((kcg * 2 + w * 16) ^ sw)) = f.v;
    }
  }

  { // V^T tile: 128 d-rows x 128B, 4x4 register transpose per task
    #pragma unroll
    for (int it = 0; it < 2; ++it) {
      int task = tid + it * 256;            // 512 tasks of 4kv x 4d
      int kvl  = (task & 15) * 4;
      int d0   = (task >> 4) * 4;
      const float* src = Vg + ((size_t)t * KVB + kvl) * DH + d0;
      float4 r0 = *reinterpret_cast<const float4*>(src);
      float4 r1 = *reinterpret_cast<const float4*>(src + DH);
      float4 r2 = *reinterpret_cast<const float4*>(src + 2 * DH);
      float4 r3 = *reinterpret_cast<const float4*>(src + 3 * DH);
      char* base = Vimg + (size_t)t * 16384;
      const int bb = kvl * 2;
      { int d = d0 + 0;
        u16x4 w4 = (u16x4){f2bf(r0.x), f2bf(r1.x), f2bf(r2.x), f2bf(r3.x)};
        *reinterpret_cast<u16x4*>(base + d * 128 + (bb ^ ((d & 15) << 3))) = w4; }
      { int d = d0 + 1;
        u16x4 w4 = (u16x4){f2bf(r0.y), f2bf(r1.y), f2bf(r2.y), f2bf(r3.y)};
        *reinterpret_cast<u16x4*>(base + d * 128 + (bb ^ ((d & 15) << 3))) = w4; }
      { int d = d0 + 2;
        u16x4 w4 = (u16x4){f2bf(r0.z), f2bf(r1.z), f2bf(r2.z), f2bf(r3.z)};
        *reinterpret_cast<u16x4*>(base + d * 128 + (bb ^ ((d & 15) << 3))) = w4; }
      { int d = d0 + 3;
        u16x4 w4 = (u16x4){f2bf(r0.w), f2bf(r1.w), f2bf(r2.w), f2bf(r3.w)};
        *reinterpret_cast<u16x4*>(base + d * 128 + (bb ^ ((d & 15) << 3))) = w4; }
    }
  }
}

// ---------------------------------------------------------------------------
// softmax over one 32-kv half (R13-proven): shfl-free steady state, tree
// pmax/psum, defer-max (T13), raw v_exp, fused exp->cvt_pk. m_run init
// -30000 so corr flushes to 0 on first tile (no guard branch).
// ---------------------------------------------------------------------------
static __device__ __forceinline__ void softmax_half(
    const f32x16& st, float& m_run, float& l_run, f32x16* oacc,
    bf16x8& pfa, bf16x8& pfb)
{
  float a0 = fmaxf(st[0],  st[1]),  a1 = fmaxf(st[2],  st[3]);
  float a2 = fmaxf(st[4],  st[5]),  a3 = fmaxf(st[6],  st[7]);
  float a4 = fmaxf(st[8],  st[9]),  a5 = fmaxf(st[10], st[11]);
  float a6 = fmaxf(st[12], st[13]), a7 = fmaxf(st[14], st[15]);
  float b0 = fmaxf(a0, a1), b1 = fmaxf(a2, a3);
  float b2 = fmaxf(a4, a5), b3 = fmaxf(a6, a7);
  float pmax = fmaxf(fmaxf(b0, b1), fmaxf(b2, b3));
  if (!__all(pmax <= m_run + 8.f)) {            // rare after warm-up (T13)
    pmax = fmaxf(pmax, __shfl_xor(pmax, 32));   // pair-max (uniform branch)
    const float m_new = fmaxf(m_run, pmax);
    const float corr  = fexp2(m_run - m_new);   // ==0 on first tile
    l_run *= corr;
    #pragma unroll
    for (int i = 0; i < 4; ++i) oacc[i] = oacc[i] * corr;
    m_run = m_new;
  }
  float e[16];
  #pragma unroll
  for (int r = 0; r < 16; ++r) e[r] = fexp2(st[r] - m_run);
  float s0 = (e[0] + e[1])   + (e[2] + e[3]);
  float s1 = (e[4] + e[5])   + (e[6] + e[7]);
  float s2 = (e[8] + e[9])   + (e[10] + e[11]);
  float s3 = (e[12] + e[13]) + (e[14] + e[15]);
  l_run += (s0 + s1) + (s2 + s3);               // per-lane partial
  union { bf16x8 v; unsigned u[4]; } fa, fb;
  fa.u[0] = pk2(e[0],  e[1]);  fa.u[1] = pk2(e[2],  e[3]);
  fa.u[2] = pk2(e[4],  e[5]);  fa.u[3] = pk2(e[6],  e[7]);
  fb.u[0] = pk2(e[8],  e[9]);  fb.u[1] = pk2(e[10], e[11]);
  fb.u[2] = pk2(e[12], e[13]); fb.u[3] = pk2(e[14], e[15]);
  pfa = fa.v; pfb = fb.v;
}

// ---------------------------------------------------------------------------
// Flash fwd: 4 waves x 32 q (QBLK=128), 32x32x16 MFMA. R13 loop verbatim.
// 1D grid with XCD-pinned chunk mapping: chunk = id % ksplit -> all blocks
// of a chunk share one XCD's L2 (512KB image stream L2-resident by
// construction). f16 split-K partials.
// ---------------------------------------------------------------------------
__global__ __launch_bounds__(256, 2)
void fa_fwd(const float* __restrict__ Qg, const char* __restrict__ Kimg,
            const char* __restrict__ Vimg, _Float16* __restrict__ Oh,
            float* __restrict__ Mp, float* __restrict__ Lp,
            int ksplit, int chunk_len)
{
  __shared__ __align__(16) char smem[2][32768];   // [buf][K 16KB | V 16KB]
  const int tid  = threadIdx.x;
  const int lane = tid & 63;
  const int wv   = tid >> 6;
  const int l31  = lane & 31;
  const int hi   = lane >> 5;

  // XCD-pinned decomposition: consecutive linear block IDs round-robin
  // XCDs, so id%ksplit pins each chunk to one XCD (perf heuristic only).
  const int id    = blockIdx.x;
  const int chunk = id % ksplit;
  const int q0blk = (id / ksplit) * QBLK;
  const int q     = q0blk + wv * 32 + l31;
  const float QSCALE = 0.1275313310087464f;       // rsqrt(128) * log2(e)

  const int tile0 = (chunk * chunk_len) >> 6;
  const int nst   = chunk_len >> 6;

  // ---- Q fragments FIRST (their waits retire before the loop).
  bf16x8 qf[8];
  {
    const float* qs = Qg + (size_t)q * DH + hi * 8;
    #pragma unroll
    for (int kc = 0; kc < 8; ++kc) {
      float4 a = *reinterpret_cast<const float4*>(qs + kc * 16);
      float4 b = *reinterpret_cast<const float4*>(qs + kc * 16 + 4);
      union { bf16x8 v; unsigned u[4]; } f;
      f.u[0] = pk2(a.x * QSCALE, a.y * QSCALE);
      f.u[1] = pk2(a.z * QSCALE, a.w * QSCALE);
      f.u[2] = pk2(b.x * QSCALE, b.y * QSCALE);
      f.u[3] = pk2(b.z * QSCALE, b.w * QSCALE);
      qf[kc] = f.v;
    }
  }

  // Per-wave DMA roles: waves 0,1 = K halves; waves 2,3 = V halves (8KB each,
  // 8 x 1KB global_load_lds_dwordx4 per wave per tile).
  const char* gbase = (wv < 2 ? Kimg : Vimg);
  const size_t goff = (size_t)(wv & 1) * 8192 + (size_t)lane * 16;
  const int    loff = (wv < 2 ? 0 : 16384) + (wv & 1) * 8192;

#define STAGE(B, T) do {                                                      \
    const char* _s = gbase + (size_t)(T) * 16384 + goff;                      \
    char* _d = &smem[B][loff];                                                \
    _Pragma("unroll")                                                         \
    for (int _i = 0; _i < 8; ++_i)                                            \
      __builtin_amdgcn_global_load_lds((gv_t*)(_s + _i * 1024),               \
                                       (sv_t*)(_d + _i * 1024), 16, 0, 0);    \
  } while (0)

  STAGE(0, tile0);
  if (nst > 1) STAGE(1, tile0 + 1);

  f32x16 oacc[4];
  #pragma unroll
  for (int i = 0; i < 4; ++i) oacc[i] = zero16();
  float m_run = -30000.f, l_run = 0.f;

  int cur = 0;
  for (int t = 0; t < nst; ++t) {
    // own 8 DMA loads for tile t done; tile t+1's 8 stay in flight (T4).
    if (t + 1 < nst) asm volatile("s_waitcnt vmcnt(8)" ::: "memory");
    else             asm volatile("s_waitcnt vmcnt(0)" ::: "memory");
    __builtin_amdgcn_sched_barrier(0);
    __builtin_amdgcn_s_barrier();          // cross-wave: tile t fully in LDS

    const char* smK = smem[cur];
    const char* smV = smem[cur] + 16384;
    const int swk = (l31 & 15) << 4;
    const int swv = (l31 & 15) << 3;

    // ---- QK^T both halves (two independent MFMA chains)
    f32x16 st0 = zero16(), st1 = zero16();
    __builtin_amdgcn_s_setprio(1);
    #pragma unroll
    for (int kc = 0; kc < 8; ++kc) {
      const int cb = (kc * 32 + hi * 16) ^ swk;
      bf16x8 a0 = *reinterpret_cast<const bf16x8*>(smK + l31 * 256 + cb);
      st0 = __builtin_amdgcn_mfma_f32_32x32x16_bf16(a0, qf[kc], st0, 0, 0, 0);
      bf16x8 a1 = *reinterpret_cast<const bf16x8*>(smK + (l31 + 32) * 256 + cb);
      st1 = __builtin_amdgcn_mfma_f32_32x32x16_bf16(a1, qf[kc], st1, 0, 0, 0);
    }
    __builtin_amdgcn_s_setprio(0);

    // ---- half 0: softmax (VALU, overlaps st1 MFMAs) then PV kv 0..31
    bf16x8 pf0a, pf0b;
    softmax_half(st0, m_run, l_run, oacc, pf0a, pf0b);
    __builtin_amdgcn_s_setprio(1);
    #pragma unroll
    for (int c = 0; c < 2; ++c) {
      const bf16x8 pb = c ? pf0b : pf0a;
      #pragma unroll
      for (int dt = 0; dt < 4; ++dt) {
        const char* vb = smV + (dt * 32 + l31) * 128;
        union { bf16x8 v; u16x4 h[2]; } a;
        a.h[0] = *reinterpret_cast<const u16x4*>(vb + ((c * 32 + 8 * hi) ^ swv));
        a.h[1] = *reinterpret_cast<const u16x4*>(vb + ((c * 32 + 16 + 8 * hi) ^ swv));
        oacc[dt] = __builtin_amdgcn_mfma_f32_32x32x16_bf16(a.v, pb, oacc[dt], 0, 0, 0);
      }
    }
    __builtin_amdgcn_s_setprio(0);

    // ---- half 1: softmax (overlaps PV0 MFMAs) then PV kv 32..63
    bf16x8 pf1a, pf1b;
    softmax_half(st1, m_run, l_run, oacc, pf1a, pf1b);
    __builtin_amdgcn_s_setprio(1);
    #pragma unroll
    for (int c = 2; c < 4; ++c) {
      const bf16x8 pb = (c & 1) ? pf1b : pf1a;
      #pragma unroll
      for (int dt = 0; dt < 4; ++dt) {
        const char* vb = smV + (dt * 32 + l31) * 128;
        union { bf16x8 v; u16x4 h[2]; } a;
        a.h[0] = *reinterpret_cast<const u16x4*>(vb + ((c * 32 + 8 * hi) ^ swv));
        a.h[1] = *reinterpret_cast<const u16x4*>(vb + ((c * 32 + 16 + 8 * hi) ^ swv));
        oacc[dt] = __builtin_amdgcn_mfma_f32_32x32x16_bf16(a.v, pb, oacc[dt], 0, 0, 0);
      }
    }
    __builtin_amdgcn_s_setprio(0);

    __builtin_amdgcn_s_barrier();          // all waves done reading buf[cur]
    if (t + 2 < nst) STAGE(cur, tile0 + t + 2);   // refill freed buffer
    cur ^= 1;
  }
#undef STAGE

  // ---- combine per-lane l partials (the only steady-state shfl, once).
  const float l_tot = l_run + __shfl_xor(l_run, 32);

  // ---- epilogue: per-wave 16KB LDS transpose (f32) -> coalesced f16 stores.
  char* base = &smem[0][0] + wv * 16384;          // [d][q32] f32, 128B rows
  #pragma unroll
  for (int dt = 0; dt < 4; ++dt)
    #pragma unroll
    for (int rg = 0; rg < 4; ++rg)
      #pragma unroll
      for (int j = 0; j < 4; ++j) {
        const int d = dt * 32 + rg * 8 + hi * 4 + j;
        *reinterpret_cast<float*>(base + d * 128 + l31 * 4) =
            oacc[dt][rg * 4 + j];
      }
  asm volatile("s_waitcnt lgkmcnt(0)" ::: "memory");
  __builtin_amdgcn_sched_barrier(0);
  const int qloc4 = lane >> 2;                    // 0..15
  const int s4    = lane & 3;
  _Float16* dstB = Oh + (size_t)chunk * NTOK * DH;
  #pragma unroll
  for (int qh = 0; qh < 2; ++qh) {
    const int qloc = qh * 16 + qloc4;
    _Float16* dst = dstB + (size_t)(q0blk + wv * 32 + qloc) * DH;
    #pragma unroll
    for (int i = 0; i < 8; ++i) {
      const int dd = s4 * 4 + i * 16;
      h16x4 v;
      v.x = (_Float16)*reinterpret_cast<float*>(base + (dd + 0) * 128 + qloc * 4);
      v.y = (_Float16)*reinterpret_cast<float*>(base + (dd + 1) * 128 + qloc * 4);
      v.z = (_Float16)*reinterpret_cast<float*>(base + (dd + 2) * 128 + qloc * 4);
      v.w = (_Float16)*reinterpret_cast<float*>(base + (dd + 3) * 128 + qloc * 4);
      *reinterpret_cast<h16x4*>(dst + dd) = v;    // 8B/lane, fully coalesced
    }
  }
  if (lane < 32) {
    const int qg = q0blk + wv * 32 + lane;
    Mp[chunk * NTOK + qg] = m_run;
    Lp[chunk * NTOK + qg] = l_tot;
  }
}

// ---------------------------------------------------------------------------
// Combine: 8 dims/thread (two float4 stores), halves duplicated M/L loads.
// ---------------------------------------------------------------------------
__global__ __launch_bounds__(256)
void fa_combine(const _Float16* __restrict__ Oh, const float* __restrict__ Mp,
                const float* __restrict__ Lp, float* __restrict__ out, int ksplit)
{
  const int gid = blockIdx.x * 256 + threadIdx.x;   // N*D/8 threads
  const int q   = gid >> 4;
  const int dv  = (gid & 15) * 8;
  float mx = -INFINITY;
  for (int c = 0; c < ksplit; ++c) mx = fmaxf(mx, Mp[c * NTOK + q]);
  float den = 0.f;
  float acc[8] = {0.f, 0.f, 0.f, 0.f, 0.f, 0.f, 0.f, 0.f};
  for (int c = 0; c < ksplit; ++c) {
    const float w = fexp2(Mp[c * NTOK + q] - mx);
    den += w * Lp[c * NTOK + q];
    const _Float16* src = Oh + (size_t)c * NTOK * DH + (size_t)q * DH + dv;
    h16x4 o0 = *reinterpret_cast<const h16x4*>(src);
    h16x4 o1 = *reinterpret_cast<const h16x4*>(src + 4);
    acc[0] += w * (float)o0.x; acc[1] += w * (float)o0.y;
    acc[2] += w * (float)o0.z; acc[3] += w * (float)o0.w;
    acc[4] += w * (float)o1.x; acc[5] += w * (float)o1.y;
    acc[6] += w * (float)o1.z; acc[7] += w * (float)o1.w;
  }
  const float r = 1.f / den;
  float4 r0; r0.x = acc[0] * r; r0.y = acc[1] * r; r0.z = acc[2] * r; r0.w = acc[3] * r;
  float4 r1; r1.x = acc[4] * r; r1.y = acc[5] * r; r1.z = acc[6] * r; r1.w = acc[7] * r;
  float* dst = out + (size_t)q * DH + dv;
  *reinterpret_cast<float4*>(dst)     = r0;
  *reinterpret_cast<float4*>(dst + 4) = r1;
}

extern "C" void kernel_launch(void* const* d_in, const int* in_sizes, int n_in,
                              void* d_out, int out_size, void* d_ws, size_t ws_size,
                              hipStream_t stream)
{
  const float* Q = (const float*)d_in[0];
  const float* K = (const float*)d_in[1];
  const float* V = (const float*)d_in[2];
  float* out = (float*)d_out;

  auto need = [](size_t ks) {   // f16 partials + f32 M/L
    return ks * (size_t)NTOK * DH * 2 + 2 * ks * (size_t)NTOK * 4;
  };
  int KS = (ws_size >= need(8)) ? 8 : (ws_size >= need(4)) ? 4 : 2;

  // K/V bf16 images live in d_out (4 MiB); combine overwrites d_out at the end.
  char* Kimg = (char*)d_out;
  char* Vimg = Kimg + (size_t)NTOK * 256;          // 2 MiB each

  _Float16* Oh = (_Float16*)d_ws;
  float* Mp = (float*)(Oh + (size_t)KS * NTOK * DH);
  float* Lp = Mp + (size_t)KS * NTOK;

  fa_prep<<<NTOK / KVB, 256, 0, stream>>>(K, V, Kimg, Vimg);
  fa_fwd<<<(NTOK / QBLK) * KS, 256, 0, stream>>>(Q, Kimg, Vimg, Oh,
                                                 Mp, Lp, KS, NTOK / KS);
  fa_combine<<<NTOK * DH / 8 / 256, 256, 0, stream>>>(Oh, Mp, Lp, out, KS);
}